// Round 21
// baseline (279.876 us; speedup 1.0000x reference)
//
#include <hip/hip_runtime.h>

#define B_   2
#define S_   2048
#define H_   2048
#define NH_  16
#define HS_  128
#define NORM_ 0.08838834764831845f          // 128^-0.5
#define L2B16 0.8304820237218407f           // log2(10000)/16

typedef unsigned short bf16_t;
typedef __bf16 bf16x8 __attribute__((ext_vector_type(8)));
typedef float  f32x4  __attribute__((ext_vector_type(4)));

__device__ __forceinline__ float b2f(bf16_t u) {
    return __uint_as_float(((unsigned int)u) << 16);
}
__device__ __forceinline__ bf16_t f2b(float f) {
    unsigned int x = __float_as_uint(f);
    x += 0x7fffu + ((x >> 16) & 1u);        // round-to-nearest-even
    return (bf16_t)(x >> 16);
}

__device__ __forceinline__ void async16(bf16_t* lds, const bf16_t* g) {
    __builtin_amdgcn_global_load_lds(
        (const __attribute__((address_space(1))) void*)g,
        (__attribute__((address_space(3))) void*)lds, 16, 0, 0);
}

__device__ __forceinline__ f32x4 mfma16(bf16x8 a, bf16x8 b, f32x4 c) {
    return __builtin_amdgcn_mfma_f32_16x16x32_bf16(a, b, c, 0, 0, 0);
}

#define BAR()        asm volatile("s_barrier" ::: "memory")
#define WAIT_VM0()   asm volatile("s_waitcnt vmcnt(0)" ::: "memory")
#define WAIT_VM8()   asm volatile("s_waitcnt vmcnt(8)" ::: "memory")

// ---------------- merged prep: cvt_bf16 + two weight transposes -------------
__device__ __forceinline__ void xpose64(const float* __restrict__ W,
                                        bf16_t* __restrict__ WT,
                                        int K, int N, int n0, int k0,
                                        int tid, float t[64][65]) {
    const int cx = tid & 15, r0 = tid >> 4;
#pragma unroll
    for (int p = 0; p < 4; p++) {
        const int row = p * 16 + r0;
        const float4 v = *(const float4*)&W[(size_t)(k0 + row) * N + n0 + cx * 4];
        t[row][cx * 4 + 0] = v.x;
        t[row][cx * 4 + 1] = v.y;
        t[row][cx * 4 + 2] = v.z;
        t[row][cx * 4 + 3] = v.w;
    }
    __syncthreads();
    const int n = tid >> 2, k8 = tid & 3;
#pragma unroll
    for (int p = 0; p < 2; p++) {
        const int kk = (k8 + p * 4) * 8;
        bf16_t o[8];
#pragma unroll
        for (int i = 0; i < 8; i++) o[i] = f2b(t[kk + i][n]);
        *(bf16x8*)&WT[(size_t)(n0 + n) * K + k0 + kk] = *(const bf16x8*)o;
    }
}

__global__ __launch_bounds__(256) void prep(const float* __restrict__ hs,
                                            bf16_t* __restrict__ X,
                                            const float* __restrict__ Wqkv,
                                            bf16_t* __restrict__ WqT,
                                            const float* __restrict__ Wd,
                                            bf16_t* __restrict__ WdT) {
    __shared__ float t[64][65];
    const int id = (int)blockIdx.x;
    const int tid = threadIdx.x;
    if (id < 4096) {                         // f32 -> bf16 convert of hs
        const size_t i = (size_t)id * 256 + tid;
        const float4* p = (const float4*)hs + i * 2;
        float4 a = p[0], b = p[1];
        bf16_t o[8] = { f2b(a.x), f2b(a.y), f2b(a.z), f2b(a.w),
                        f2b(b.x), f2b(b.y), f2b(b.z), f2b(b.w) };
        *((bf16x8*)X + i) = *(const bf16x8*)o;
    } else if (id < 4096 + 3072) {           // Wqkv^T (96 x 32 tiles)
        const int q = id - 4096;
        xpose64(Wqkv, WqT, 2048, 6144, (q % 96) * 64, (q / 96) * 64, tid, t);
    } else {                                 // Wd^T (32 x 32 tiles)
        const int q = id - 7168;
        xpose64(Wd, WdT, 2048, 2048, (q % 32) * 64, (q / 32) * 64, tid, t);
    }
}

// ---------------- BK=32 folded-layout staging (256-thread blocks) -----------
// LDS row = 2 orig rows (128B, 8 x 16B chunks). Chunk slot within folded row:
// ((r&1)*4 + kc) ^ ((r>>1)&7).  Fragment reads (16 lanes, fixed kc=ls) hit
// each bank exactly 2x (free). Dest is linear; source carries the inverse.
__device__ __forceinline__ void st256f(bf16_t* lds, const bf16_t* g,
                                       int K, int part, int tid) {
    const int c = part * 256 + tid;          // 16B-chunk index (0..511)
    const int R = c >> 3, s = c & 7;
    const int u = s ^ (R & 7);
    const int r = 2 * R + (u >> 2);
    const int kc = u & 3;
    async16(lds + c * 8, g + (size_t)r * K + kc * 8);
}

// fragment at row r, k-chunk ls (8 bf16)
#define FOFF(r) (((r) >> 1) * 64 + (((((r) & 1) << 2) + ls) ^ (((r) >> 1) & 7)) * 8)

#define LDA4(ab) do {                                                          \
    _Pragma("unroll")                                                          \
    for (int m = 0; m < 4; m++) {                                              \
        const int r = wm * 64 + m * 16 + lr;                                   \
        af[m] = *(const bf16x8*)&(ab)[FOFF(r)];                                \
    }                                                                          \
} while (0)

#define LDB4F(bb) do {                                                         \
    _Pragma("unroll")                                                          \
    for (int n = 0; n < 4; n++) {                                              \
        const int r = wn * 64 + n * 16 + lr;                                   \
        bf[n] = *(const bf16x8*)&(bb)[FOFF(r)];                                \
    }                                                                          \
} while (0)

#define MMA16() do {                                                           \
    __builtin_amdgcn_s_setprio(1);                                             \
    _Pragma("unroll")                                                          \
    for (int n = 0; n < 4; n++)                                                \
        _Pragma("unroll")                                                      \
        for (int m = 0; m < 4; m++)                                            \
            acc[m][n] = mfma16(af[m], bf[n], acc[m][n]);                       \
    __builtin_amdgcn_s_setprio(0);                                             \
} while (0)

// ---------------- fused QKV GEMM v3: 128x128, BK=32, 4 blocks/CU ------------
// 256 thr (4 waves 2m x 2n, per-wave 64x64), 32KB LDS. grid (48,32)=1536
// blocks = 6/CU (4 resident). which = bx%3, nh = bx/3 (r14 decode); RoPE
// pair (d, d+16) = frags n0,n1 of wn==0 — in-thread.
__global__ __launch_bounds__(256, 4) void gemm_qkv_fused(
        const bf16_t* __restrict__ A, const bf16_t* __restrict__ BT,
        const float* __restrict__ bias, const int* __restrict__ pos_ids,
        bf16_t* __restrict__ Qo, bf16_t* __restrict__ Ko,
        bf16_t* __restrict__ Vt, int M, int N, int K) {
    __shared__ __align__(16) bf16_t As[2][128 * 32];
    __shared__ __align__(16) bf16_t Bs[2][128 * 32];

    const int id  = (int)(blockIdx.y * gridDim.x + blockIdx.x);   // 0..1535
    const int xcd = id & 7, j0 = id >> 3;                         // j0 0..191
    const int bx  = (xcd & 3) * 12 + (j0 % 12);    // 0..47
    const int by  = (xcd >> 2) * 16 + (j0 / 12);   // 0..31

    const int tid = threadIdx.x;
    const int wid = tid >> 6, lane = tid & 63;
    const int lr = lane & 15, ls = lane >> 4;
    const int wm = wid >> 1, wn = wid & 1;
    const size_t m0 = (size_t)by * 128, n0 = (size_t)bx * 128;

    const bf16_t* Ab = A + m0 * K;
    const bf16_t* Bb = BT + n0 * K;

    f32x4 acc[4][4];
#pragma unroll
    for (int m = 0; m < 4; m++)
#pragma unroll
        for (int n = 0; n < 4; n++) acc[m][n] = (f32x4){0.f, 0.f, 0.f, 0.f};
    bf16x8 af[4], bf[4];

    st256f(As[0], Ab, K, 0, tid);
    st256f(As[0], Ab, K, 1, tid);
    st256f(Bs[0], Bb, K, 0, tid);
    st256f(Bs[0], Bb, K, 1, tid);
    WAIT_VM0();
    BAR();

    const int nt = K >> 5;                       // 64 tiles
#pragma unroll 1
    for (int i = 0; i < nt; ++i) {
        const int c = i & 1;
        const bf16_t* Ac = As[c];
        const bf16_t* Bc = Bs[c];
        if (i + 1 < nt) {
            const size_t ko = (size_t)(i + 1) * 32;
            st256f(As[c ^ 1], Ab + ko, K, 0, tid);
            st256f(As[c ^ 1], Ab + ko, K, 1, tid);
            st256f(Bs[c ^ 1], Bb + ko, K, 0, tid);
            st256f(Bs[c ^ 1], Bb + ko, K, 1, tid);
        }
        __builtin_amdgcn_sched_barrier(0);
        LDA4(Ac);
        LDB4F(Bc);
        MMA16();
        WAIT_VM0();
        BAR();
    }

    // -------- epilogue: bias + RoPE + scatter --------
    const int which = bx % 3;                    // 0=Q 1=K 2=V
    const int nh    = bx / 3;
    float bv[4];
#pragma unroll
    for (int n = 0; n < 4; n++) bv[n] = bias[n0 + wn * 64 + n * 16 + lr];
#pragma unroll
    for (int mm = 0; mm < 4; mm++)
#pragma unroll
        for (int n = 0; n < 4; n++)
#pragma unroll
            for (int j = 0; j < 4; j++) acc[mm][n][j] += bv[n];

    if (which == 2) {                            // V -> V^T[bh][d][s]
#pragma unroll
        for (int mm = 0; mm < 4; mm++) {
            const int row0 = (int)m0 + wm * 64 + mm * 16 + ls * 4;
            const int b = row0 >> 11, s0 = row0 & 2047;
            const size_t bh = (size_t)(b * NH_ + nh);
#pragma unroll
            for (int n = 0; n < 4; n++) {
                const int d = wn * 64 + n * 16 + lr;
                bf16_t o[4];
#pragma unroll
                for (int j = 0; j < 4; j++) o[j] = f2b(acc[mm][n][j]);
                *(uint2*)&Vt[(bh * HS_ + d) * S_ + s0] = *(const uint2*)o;
            }
        }
    } else {
        bf16_t* O = which ? Ko : Qo;
        const bool rot = (wn == 0);              // frags n0 (d=lr), n1 (d=16+lr)
        const float invf = __builtin_exp2f(-(float)lr * L2B16);
#pragma unroll
        for (int mm = 0; mm < 4; mm++) {
            const int row0 = (int)m0 + wm * 64 + mm * 16 + ls * 4;
            const int b = row0 >> 11;
            const size_t bh = (size_t)(b * NH_ + nh);
#pragma unroll
            for (int j = 0; j < 4; j++) {
                const int row = row0 + j;
                const int s = row & 2047;
                if (rot) {
                    const float th = (float)pos_ids[row] * invf;
                    const float cth = __cosf(th), sth = __sinf(th);
                    const float x = acc[mm][0][j], y = acc[mm][1][j];
                    acc[mm][0][j] = x * cth - y * sth;
                    acc[mm][1][j] = y * cth + x * sth;
                }
                bf16_t* dst = O + (bh * S_ + s) * HS_ + wn * 64 + lr;
#pragma unroll
                for (int n = 0; n < 4; n++) dst[n * 16] = f2b(acc[mm][n][j]);
            }
        }
    }
}

// ---------------- dense GEMM v2: 128x128, BK=32, all-resident ---------------
__global__ __launch_bounds__(256, 4) void gemm_dense(const bf16_t* __restrict__ A,
                                                     const bf16_t* __restrict__ BT,
                                                     const float* __restrict__ bias,
                                                     float* __restrict__ C,
                                                     int M, int N, int K) {
    __shared__ __align__(16) bf16_t As[2][128 * 32];
    __shared__ __align__(16) bf16_t Bs[2][128 * 32];

    const int id  = (int)(blockIdx.y * gridDim.x + blockIdx.x);   // 0..511
    const int xcd = id & 7, j0 = id >> 3;
    const int bx  = (xcd & 1) * 8 + (j0 & 7);      // 0..15
    const int by  = (xcd >> 1) * 8 + (j0 >> 3);    // 0..31

    const int tid = threadIdx.x;
    const int wid = tid >> 6, lane = tid & 63;
    const int lr = lane & 15, ls = lane >> 4;
    const int wm = wid >> 1, wn = wid & 1;
    const size_t m0 = (size_t)by * 128, n0 = (size_t)bx * 128;

    const bf16_t* Ab = A + m0 * K;
    const bf16_t* Bb = BT + n0 * K;

    f32x4 acc[4][4];
#pragma unroll
    for (int m = 0; m < 4; m++)
#pragma unroll
        for (int n = 0; n < 4; n++) acc[m][n] = (f32x4){0.f, 0.f, 0.f, 0.f};
    bf16x8 af[4], bf[4];

    st256f(As[0], Ab, K, 0, tid);
    st256f(As[0], Ab, K, 1, tid);
    st256f(Bs[0], Bb, K, 0, tid);
    st256f(Bs[0], Bb, K, 1, tid);
    WAIT_VM0();
    BAR();

    const int nt = K >> 5;
#pragma unroll 1
    for (int i = 0; i < nt; ++i) {
        const int c = i & 1;
        const bf16_t* Ac = As[c];
        const bf16_t* Bc = Bs[c];
        if (i + 1 < nt) {
            const size_t ko = (size_t)(i + 1) * 32;
            st256f(As[c ^ 1], Ab + ko, K, 0, tid);
            st256f(As[c ^ 1], Ab + ko, K, 1, tid);
            st256f(Bs[c ^ 1], Bb + ko, K, 0, tid);
            st256f(Bs[c ^ 1], Bb + ko, K, 1, tid);
        }
        __builtin_amdgcn_sched_barrier(0);
        LDA4(Ac);
        LDB4F(Bc);
        MMA16();
        WAIT_VM0();
        BAR();
    }

    float bv[4];
#pragma unroll
    for (int n = 0; n < 4; n++) bv[n] = bias[n0 + wn * 64 + n * 16 + lr];
#pragma unroll
    for (int mm = 0; mm < 4; mm++)
#pragma unroll
        for (int n = 0; n < 4; n++)
#pragma unroll
            for (int j = 0; j < 4; j++) {
                const size_t row = m0 + wm * 64 + mm * 16 + ls * 4 + j;
                const size_t col = n0 + wn * 64 + n * 16 + lr;
                C[row * N + col] = acc[mm][n][j] + bv[n];
            }
}

// ---------------- causal flash attention (r8 structure, best known) ---------
__device__ __forceinline__ void attn_stage(bf16_t* Kd, bf16_t* Vd,
                                           const bf16_t* Kg, const bf16_t* Vg,
                                           int kv0, int wid, int lane) {
#pragma unroll
    for (int jj = 0; jj < 4; jj++) {
        const int c = (wid << 2) + jj;
        const int rk = (c << 2) + (lane >> 4);        // K row 0..63
        async16(Kd + c * 512,
                Kg + (size_t)(kv0 + rk) * HS_ + (((lane & 15) ^ (rk & 7)) << 3));
        const int rv = (c << 3) + (lane >> 3);        // V^T row 0..127
        async16(Vd + c * 512,
                Vg + (size_t)rv * S_ + kv0 + (((lane & 7) ^ (rv & 7)) << 3));
    }
}

__global__ __launch_bounds__(256) void attn_fwd(const bf16_t* __restrict__ Q,
                                                const bf16_t* __restrict__ Kv,
                                                const bf16_t* __restrict__ Vt,
                                                const float* __restrict__ amask,
                                                bf16_t* __restrict__ ctx) {
    __shared__ __align__(16) bf16_t Ks[2][64 * 128];
    __shared__ __align__(16) bf16_t Vs[2][128 * 64];
    __shared__ __align__(16) bf16_t Ps[4][16 * 72];

    const int id = (int)(blockIdx.x + (blockIdx.y << 4));     // 0..511
    const int wg = ((id & 7) << 6) + (id >> 3);               // XCD-bijective
    const int pair = wg & 15;
    const int bh = wg >> 4;
    const int b = bh >> 4, h = bh & 15;
    const int tid = threadIdx.x, wid = tid >> 6, lane = tid & 63;
    const int lr = lane & 15, ls = lane >> 4;
    const float* am = amask + (size_t)b * S_;
    const bf16_t* Kg = Kv + (size_t)bh * S_ * HS_;
    const bf16_t* Vg = Vt + (size_t)bh * HS_ * S_;

#pragma unroll 1
    for (int half = 0; half < 2; ++half) {
        const int qt = half ? pair : (31 - pair);
        const int q0 = qt << 6;
        const int qrow = q0 + wid * 16 + lr;     // this lane's q-row

        bf16x8 qf[4];
        const bf16_t* qp = Q + ((size_t)bh * S_ + qrow) * HS_;
#pragma unroll
        for (int dk = 0; dk < 4; dk++) qf[dk] = *(const bf16x8*)(qp + dk * 32 + ls * 8);

        float mrun = -3.0e38f, lrun = 0.f;
        f32x4 oacc[8];
#pragma unroll
        for (int dt = 0; dt < 8; dt++) oacc[dt] = (f32x4){0.f, 0.f, 0.f, 0.f};

        attn_stage(Ks[0], Vs[0], Kg, Vg, 0, wid, lane);

#pragma unroll 1
        for (int step = 0; step <= qt; ++step) {
            const int cur = step & 1;
            const int kv0 = step << 6;
            if (step < qt) {
                attn_stage(Ks[cur ^ 1], Vs[cur ^ 1], Kg, Vg, (step + 1) << 6, wid, lane);
                WAIT_VM8();
            } else {
                WAIT_VM0();
            }
            BAR();

            // swapped QK^T
            f32x4 sacc[4];
#pragma unroll
            for (int t = 0; t < 4; t++) sacc[t] = (f32x4){0.f, 0.f, 0.f, 0.f};
#pragma unroll
            for (int t = 0; t < 4; t++)
#pragma unroll
                for (int dk = 0; dk < 4; dk++) {
                    const int row = t * 16 + lr;
                    bf16x8 kf = *(const bf16x8*)
                        &Ks[cur][row * 128 + (((dk * 4 + ls) ^ (row & 7)) << 3)];
                    sacc[t] = mfma16(kf, qf[dk], sacc[t]);
                }

            const bool diag = (step == qt);
            float sv[4][4];
            float rmax = -3.0e38f;
#pragma unroll
            for (int t = 0; t < 4; t++) {
                const float4 amv = *(const float4*)&am[kv0 + t * 16 + ls * 4];
                const float amj[4] = { amv.x, amv.y, amv.z, amv.w };
#pragma unroll
                for (int j = 0; j < 4; j++) {
                    const int kvp = kv0 + t * 16 + ls * 4 + j;
                    float v = sacc[t][j] * NORM_ + amj[j];
                    if (diag && kvp > qrow) v = -3.0e38f;
                    sv[t][j] = v;
                    rmax = fmaxf(rmax, v);
                }
            }
            rmax = fmaxf(rmax, __shfl_xor(rmax, 16));
            rmax = fmaxf(rmax, __shfl_xor(rmax, 32));

            if (!__all((int)(rmax <= mrun))) {
                const float mnew = fmaxf(mrun, rmax);
                const float sc = __expf(mrun - mnew);
                lrun *= sc;
                mrun = mnew;
                float scb[4];
#pragma unroll
                for (int j = 0; j < 4; j++) scb[j] = __shfl(sc, ls * 4 + j);
#pragma unroll
                for (int dt = 0; dt < 8; dt++)
#pragma unroll
                    for (int j = 0; j < 4; j++) oacc[dt][j] *= scb[j];
            }

            float psum = 0.f;
#pragma unroll
            for (int t = 0; t < 4; t++) {
                const float p0 = __expf(sv[t][0] - mrun);
                const float p1 = __expf(sv[t][1] - mrun);
                const float p2 = __expf(sv[t][2] - mrun);
                const float p3 = __expf(sv[t][3] - mrun);
                psum += (p0 + p1) + (p2 + p3);
                const unsigned pk0 = (unsigned)f2b(p0) | ((unsigned)f2b(p1) << 16);
                const unsigned pk1 = (unsigned)f2b(p2) | ((unsigned)f2b(p3) << 16);
                *(unsigned*)&Ps[wid][lr * 72 + t * 16 + ls * 4]     = pk0;
                *(unsigned*)&Ps[wid][lr * 72 + t * 16 + ls * 4 + 2] = pk1;
            }
            psum += __shfl_xor(psum, 16);
            psum += __shfl_xor(psum, 32);
            lrun += psum;

            bf16x8 pf[2];
#pragma unroll
            for (int hh = 0; hh < 2; hh++)
                pf[hh] = *(const bf16x8*)&Ps[wid][lr * 72 + hh * 32 + ls * 8];
#pragma unroll
            for (int dt = 0; dt < 8; dt++)
#pragma unroll
                for (int hh = 0; hh < 2; hh++) {
                    const int vrow = dt * 16 + lr;
                    bf16x8 vf = *(const bf16x8*)
                        &Vs[cur][vrow * 64 + (((hh * 4 + ls) ^ (vrow & 7)) << 3)];
                    oacc[dt] = mfma16(pf[hh], vf, oacc[dt]);
                }
            BAR();
        }

        const float inv = 1.0f / lrun;           // q=lr layout
        float invj[4];
#pragma unroll
        for (int j = 0; j < 4; j++) invj[j] = __shfl(inv, ls * 4 + j);
#pragma unroll
        for (int j = 0; j < 4; j++) {
            bf16_t* dst = ctx + ((size_t)b * S_ + q0 + wid * 16 + ls * 4 + j) * H_ + h * HS_;
#pragma unroll
            for (int dt = 0; dt < 8; dt++) dst[dt * 16 + lr] = f2b(oacc[dt][j] * invj[j]);
        }
    }
}

extern "C" void kernel_launch(void* const* d_in, const int* in_sizes, int n_in,
                              void* d_out, int out_size, void* d_ws, size_t ws_size,
                              hipStream_t stream) {
    const float* hs   = (const float*)d_in[0];
    const float* am   = (const float*)d_in[1];
    const int*   pos  = (const int*)d_in[2];
    const float* Wqkv = (const float*)d_in[3];
    const float* bqkv = (const float*)d_in[4];
    const float* Wd   = (const float*)d_in[5];
    const float* bd   = (const float*)d_in[6];
    float* out = (float*)d_out;
    char*  ws  = (char*)d_ws;

    const size_t MB = 1024 * 1024;
    bf16_t* X    = (bf16_t*)(ws);              // 16 MB (reused as ctx)
    bf16_t* WqT  = (bf16_t*)(ws + 16 * MB);    // 24 MB
    bf16_t* WdT  = (bf16_t*)(ws + 40 * MB);    // 8 MB
    bf16_t* Qb   = (bf16_t*)(ws + 48 * MB);    // 16 MB
    bf16_t* Kb   = (bf16_t*)(ws + 64 * MB);    // 16 MB
    bf16_t* Vtb  = (bf16_t*)(ws + 80 * MB);    // 16 MB
    bf16_t* ctx  = X;

    prep<<<8192, 256, 0, stream>>>(hs, X, Wqkv, WqT, Wd, WdT);
    gemm_qkv_fused<<<dim3(48, 32), 256, 0, stream>>>(X, WqT, bqkv, pos,
                                                     Qb, Kb, Vtb, 4096, 6144, 2048);
    attn_fwd<<<dim3(16, 32), 256, 0, stream>>>(Qb, Kb, Vtb, am, ctx);
    gemm_dense<<<dim3(16, 32), 256, 0, stream>>>(ctx, WdT, bd, out, 4096, 2048, 2048);
}

// Round 22
// 250.371 us; speedup vs baseline: 1.1178x; 1.1178x over previous
//
#include <hip/hip_runtime.h>

#define B_   2
#define S_   2048
#define H_   2048
#define NH_  16
#define HS_  128
#define NORM_ 0.08838834764831845f          // 128^-0.5
#define L2B16 0.8304820237218407f           // log2(10000)/16

typedef unsigned short bf16_t;
typedef __bf16 bf16x8 __attribute__((ext_vector_type(8)));
typedef float  f32x4  __attribute__((ext_vector_type(4)));

__device__ __forceinline__ float b2f(bf16_t u) {
    return __uint_as_float(((unsigned int)u) << 16);
}
__device__ __forceinline__ bf16_t f2b(float f) {
    unsigned int x = __float_as_uint(f);
    x += 0x7fffu + ((x >> 16) & 1u);        // round-to-nearest-even
    return (bf16_t)(x >> 16);
}

__device__ __forceinline__ void async16(bf16_t* lds, const bf16_t* g) {
    __builtin_amdgcn_global_load_lds(
        (const __attribute__((address_space(1))) void*)g,
        (__attribute__((address_space(3))) void*)lds, 16, 0, 0);
}

__device__ __forceinline__ f32x4 mfma16(bf16x8 a, bf16x8 b, f32x4 c) {
    return __builtin_amdgcn_mfma_f32_16x16x32_bf16(a, b, c, 0, 0, 0);
}

#define BAR()        asm volatile("s_barrier" ::: "memory")
#define WAIT_VM0()   asm volatile("s_waitcnt vmcnt(0)" ::: "memory")
#define WAIT_VM8()   asm volatile("s_waitcnt vmcnt(8)" ::: "memory")

// ---------------- merged prep: cvt_bf16 + two weight transposes -------------
__device__ __forceinline__ void xpose64(const float* __restrict__ W,
                                        bf16_t* __restrict__ WT,
                                        int K, int N, int n0, int k0,
                                        int tid, float t[64][65]) {
    const int cx = tid & 15, r0 = tid >> 4;
#pragma unroll
    for (int p = 0; p < 4; p++) {
        const int row = p * 16 + r0;
        const float4 v = *(const float4*)&W[(size_t)(k0 + row) * N + n0 + cx * 4];
        t[row][cx * 4 + 0] = v.x;
        t[row][cx * 4 + 1] = v.y;
        t[row][cx * 4 + 2] = v.z;
        t[row][cx * 4 + 3] = v.w;
    }
    __syncthreads();
    const int n = tid >> 2, k8 = tid & 3;
#pragma unroll
    for (int p = 0; p < 2; p++) {
        const int kk = (k8 + p * 4) * 8;
        bf16_t o[8];
#pragma unroll
        for (int i = 0; i < 8; i++) o[i] = f2b(t[kk + i][n]);
        *(bf16x8*)&WT[(size_t)(n0 + n) * K + k0 + kk] = *(const bf16x8*)o;
    }
}

__global__ __launch_bounds__(256) void prep(const float* __restrict__ hs,
                                            bf16_t* __restrict__ X,
                                            const float* __restrict__ Wqkv,
                                            bf16_t* __restrict__ WqT,
                                            const float* __restrict__ Wd,
                                            bf16_t* __restrict__ WdT) {
    __shared__ float t[64][65];
    const int id = (int)blockIdx.x;
    const int tid = threadIdx.x;
    if (id < 4096) {                         // f32 -> bf16 convert of hs
        const size_t i = (size_t)id * 256 + tid;
        const float4* p = (const float4*)hs + i * 2;
        float4 a = p[0], b = p[1];
        bf16_t o[8] = { f2b(a.x), f2b(a.y), f2b(a.z), f2b(a.w),
                        f2b(b.x), f2b(b.y), f2b(b.z), f2b(b.w) };
        *((bf16x8*)X + i) = *(const bf16x8*)o;
    } else if (id < 4096 + 3072) {           // Wqkv^T (96 x 32 tiles)
        const int q = id - 4096;
        xpose64(Wqkv, WqT, 2048, 6144, (q % 96) * 64, (q / 96) * 64, tid, t);
    } else {                                 // Wd^T (32 x 32 tiles)
        const int q = id - 7168;
        xpose64(Wd, WdT, 2048, 2048, (q % 32) * 64, (q / 32) * 64, tid, t);
    }
}

// ---------------- shared staging helper (512-thread blocks) ----------------
__device__ __forceinline__ void st512(bf16_t* lds, const bf16_t* g,
                                      int K, int part, int tid) {
    const int idx = part * 512 + tid;
    const int row = idx >> 3, slot = idx & 7;
    async16(lds + idx * 8, g + (size_t)row * K + ((slot ^ (row & 7)) << 3));
}

#define LDAQ2(dst, ab, q) do {                                                 \
    _Pragma("unroll")                                                          \
    for (int m = 0; m < 2; m++)                                                \
        _Pragma("unroll")                                                      \
        for (int ks = 0; ks < 2; ks++) {                                       \
            const int r = wm * 64 + (q) * 32 + m * 16 + lr;                    \
            dst[m][ks] = *(const bf16x8*)                                      \
                &(ab)[r * 64 + (((ks * 4 + ls) ^ (r & 7)) << 3)];              \
        }                                                                      \
} while (0)

#define LDB3(bb) do {                                                          \
    _Pragma("unroll")                                                          \
    for (int n = 0; n < 3; n++)                                                \
        _Pragma("unroll")                                                      \
        for (int ks = 0; ks < 2; ks++) {                                       \
            const int r = wn * 48 + n * 16 + lr;                               \
            bfr[n][ks] = *(const bf16x8*)                                      \
                &(bb)[r * 64 + (((ks * 4 + ls) ^ (r & 7)) << 3)];              \
        }                                                                      \
} while (0)

#define MMA3(q, src) do {                                                      \
    __builtin_amdgcn_s_setprio(1);                                             \
    _Pragma("unroll")                                                          \
    for (int ks = 0; ks < 2; ks++)                                             \
        _Pragma("unroll")                                                      \
        for (int n = 0; n < 3; n++)                                            \
            _Pragma("unroll")                                                  \
            for (int m = 0; m < 2; m++)                                        \
                acc[(q) * 2 + m][n] =                                          \
                    mfma16(src[m][ks], bfr[n][ks], acc[(q) * 2 + m][n]);       \
    __builtin_amdgcn_s_setprio(0);                                             \
} while (0)

#define LDB2D(bb) do {                                                         \
    _Pragma("unroll")                                                          \
    for (int n = 0; n < 2; n++)                                                \
        _Pragma("unroll")                                                      \
        for (int ks = 0; ks < 2; ks++) {                                       \
            const int r = wn * 32 + n * 16 + lr;                               \
            bfr[n][ks] = *(const bf16x8*)                                      \
                &(bb)[r * 64 + (((ks * 4 + ls) ^ (r & 7)) << 3)];              \
        }                                                                      \
} while (0)

#define MMA2D(q, src) do {                                                     \
    __builtin_amdgcn_s_setprio(1);                                             \
    _Pragma("unroll")                                                          \
    for (int ks = 0; ks < 2; ks++)                                             \
        _Pragma("unroll")                                                      \
        for (int n = 0; n < 2; n++)                                            \
            _Pragma("unroll")                                                  \
            for (int m = 0; m < 2; m++)                                        \
                acc[(q) * 2 + m][n] =                                          \
                    mfma16(src[m][ks], bfr[n][ks], acc[(q) * 2 + m][n]);       \
    __builtin_amdgcn_s_setprio(0);                                             \
} while (0)

// ---------------- dense GEMM: 128x128, BK=64 dbuf, 64KB LDS (2 blocks/CU) ---
__global__ __launch_bounds__(512, 2) void gemm_dense(const bf16_t* __restrict__ A,
                                                     const bf16_t* __restrict__ BT,
                                                     const float* __restrict__ bias,
                                                     float* __restrict__ C,
                                                     int M, int N, int K) {
    __shared__ __align__(16) bf16_t As[2][128 * 64];
    __shared__ __align__(16) bf16_t Bs[2][128 * 64];

    const int id  = (int)(blockIdx.y * gridDim.x + blockIdx.x);   // 0..511
    const int xcd = id & 7, j0 = id >> 3;
    const int bx  = (xcd & 1) * 8 + (j0 & 7);      // 0..15
    const int by  = (xcd >> 1) * 8 + (j0 >> 3);    // 0..31

    const int tid = threadIdx.x;
    const int wid = tid >> 6, lane = tid & 63;
    const int lr = lane & 15, ls = lane >> 4;
    const int wm = wid >> 2, wn = wid & 3;
    const size_t m0 = (size_t)by * 128, n0 = (size_t)bx * 128;

    const bf16_t* Ab = A + m0 * K;
    const bf16_t* Bb = BT + n0 * K;

    f32x4 acc[4][2];
#pragma unroll
    for (int m = 0; m < 4; m++)
#pragma unroll
        for (int n = 0; n < 2; n++) acc[m][n] = (f32x4){0.f, 0.f, 0.f, 0.f};
    bf16x8 bfr[2][2];
    bf16x8 afP[2][2], afQ[2][2];

#pragma unroll
    for (int p = 0; p < 2; p++) st512(As[0], Ab, K, p, tid);
#pragma unroll
    for (int p = 0; p < 2; p++) st512(Bs[0], Bb, K, p, tid);
    WAIT_VM0();
    BAR();

    const int nt = K >> 6;
#pragma unroll 1
    for (int i = 0; i < nt; ++i) {
        const int c = i & 1;
        const bf16_t* Ac = As[c];
        const bf16_t* Bc = Bs[c];
        if (i + 1 < nt) {
            const size_t ko = (size_t)(i + 1) * 64;
            bf16_t* Ad = As[c ^ 1];
            bf16_t* Bd = Bs[c ^ 1];
#pragma unroll
            for (int p = 0; p < 2; p++) st512(Ad, Ab + ko, K, p, tid);
#pragma unroll
            for (int p = 0; p < 2; p++) st512(Bd, Bb + ko, K, p, tid);
        }
        __builtin_amdgcn_sched_barrier(0);
        LDAQ2(afP, Ac, 0);
        LDB2D(Bc);
        LDAQ2(afQ, Ac, 1);
        MMA2D(0, afP);
        MMA2D(1, afQ);
        WAIT_VM0();
        BAR();
    }

    float bv[2];
#pragma unroll
    for (int n = 0; n < 2; n++) bv[n] = bias[n0 + wn * 32 + n * 16 + lr];
#pragma unroll
    for (int mm = 0; mm < 4; mm++)
#pragma unroll
        for (int n = 0; n < 2; n++)
#pragma unroll
            for (int j = 0; j < 4; j++) {
                const size_t row = m0 + wm * 64 + mm * 16 + ls * 4 + j;
                const size_t col = n0 + wn * 32 + n * 16 + lr;
                C[row * N + col] = acc[mm][n][j] + bv[n];
            }
}

// ---------------- fused QKV GEMM: 128x192, 80KB LDS (2 blocks/CU) -----------
__global__ __launch_bounds__(512, 2) void gemm_qkv_fused(
        const bf16_t* __restrict__ A, const bf16_t* __restrict__ BT,
        const float* __restrict__ bias, const int* __restrict__ pos_ids,
        bf16_t* __restrict__ Qo, bf16_t* __restrict__ Ko,
        bf16_t* __restrict__ Vt, int M, int N, int K) {
    __shared__ __align__(16) bf16_t As[2][128 * 64];
    __shared__ __align__(16) bf16_t Bs[2][192 * 64];

    const int id  = (int)(blockIdx.y * gridDim.x + blockIdx.x);   // 0..1023
    const int xcd = id & 7, j0 = id >> 3;                         // j0 0..127
    const int bx  = (xcd & 3) * 8 + (j0 & 7);      // 0..31
    const int by  = (xcd >> 2) * 16 + (j0 >> 3);   // 0..31

    const int tid = threadIdx.x;
    const int wid = tid >> 6, lane = tid & 63;
    const int lr = lane & 15, ls = lane >> 4;
    const int wm = wid >> 2, wn = wid & 3;
    const size_t m0 = (size_t)by * 128, n0 = (size_t)bx * 192;

    const bf16_t* Ab = A + m0 * K;
    const bf16_t* Bb = BT + n0 * K;

    f32x4 acc[4][3];
#pragma unroll
    for (int m = 0; m < 4; m++)
#pragma unroll
        for (int n = 0; n < 3; n++) acc[m][n] = (f32x4){0.f, 0.f, 0.f, 0.f};
    bf16x8 bfr[3][2];
    bf16x8 afP[2][2], afQ[2][2];

#pragma unroll
    for (int p = 0; p < 2; p++) st512(As[0], Ab, K, p, tid);
#pragma unroll
    for (int p = 0; p < 3; p++) st512(Bs[0], Bb, K, p, tid);
    WAIT_VM0();
    BAR();

    const int nt = K >> 6;
#pragma unroll 1
    for (int i = 0; i < nt; ++i) {
        const int c = i & 1;
        const bf16_t* Ac = As[c];
        const bf16_t* Bc = Bs[c];
        if (i + 1 < nt) {
            const size_t ko = (size_t)(i + 1) * 64;
            bf16_t* Ad = As[c ^ 1];
            bf16_t* Bd = Bs[c ^ 1];
#pragma unroll
            for (int p = 0; p < 2; p++) st512(Ad, Ab + ko, K, p, tid);
#pragma unroll
            for (int p = 0; p < 3; p++) st512(Bd, Bb + ko, K, p, tid);
        }
        __builtin_amdgcn_sched_barrier(0);
        LDAQ2(afP, Ac, 0);
        LDB3(Bc);
        LDAQ2(afQ, Ac, 1);
        MMA3(0, afP);
        MMA3(1, afQ);
        WAIT_VM0();
        BAR();
    }

    // -------- epilogue: bias, RoPE (one cross-wave exchange), scatter --------
    const bool evenbx = ((bx & 1) == 0);
    const int  nh     = bx >> 1;
    {
        float bv[3];
#pragma unroll
        for (int n = 0; n < 3; n++) bv[n] = bias[n0 + wn * 48 + n * 16 + lr];
#pragma unroll
        for (int mm = 0; mm < 4; mm++)
#pragma unroll
            for (int n = 0; n < 3; n++)
#pragma unroll
                for (int j = 0; j < 4; j++) acc[mm][n][j] += bv[n];
    }

    float* XB = (float*)&As[0][0];               // dead after final BAR
    if (evenbx && wn == 2) {
#pragma unroll
        for (int mm = 0; mm < 4; mm++)
#pragma unroll
            for (int j = 0; j < 4; j++)
                XB[((((wm * 4 + mm) * 4 + ls) * 4 + j) * 16) + lr] = acc[mm][2][j];
    }
    if (evenbx && wn == 3) {
#pragma unroll
        for (int mm = 0; mm < 4; mm++)
#pragma unroll
            for (int j = 0; j < 4; j++)
                XB[2048 + ((((wm * 4 + mm) * 4 + ls) * 4 + j) * 16) + lr] = acc[mm][0][j];
    }
    __syncthreads();

    const float invf = __builtin_exp2f(-(float)lr * L2B16);

    if (evenbx && wn == 0) {                     // Q rot
#pragma unroll
        for (int mm = 0; mm < 4; mm++) {
            const int row0 = (int)m0 + wm * 64 + mm * 16 + ls * 4;
#pragma unroll
            for (int j = 0; j < 4; j++) {
                const float th = (float)pos_ids[row0 + j] * invf;
                const float c = __cosf(th), sn = __sinf(th);
                const float x = acc[mm][0][j], y = acc[mm][1][j];
                acc[mm][0][j] = x * c - y * sn;
                acc[mm][1][j] = y * c + x * sn;
            }
        }
    }
    if (evenbx && wn == 2) {                     // K low rot
#pragma unroll
        for (int mm = 0; mm < 4; mm++) {
            const int row0 = (int)m0 + wm * 64 + mm * 16 + ls * 4;
#pragma unroll
            for (int j = 0; j < 4; j++) {
                const float th = (float)pos_ids[row0 + j] * invf;
                const float c = __cosf(th), sn = __sinf(th);
                const float y = XB[2048 + ((((wm * 4 + mm) * 4 + ls) * 4 + j) * 16) + lr];
                acc[mm][2][j] = acc[mm][2][j] * c - y * sn;
            }
        }
    }
    if (evenbx && wn == 3) {                     // K high rot
#pragma unroll
        for (int mm = 0; mm < 4; mm++) {
            const int row0 = (int)m0 + wm * 64 + mm * 16 + ls * 4;
#pragma unroll
            for (int j = 0; j < 4; j++) {
                const float th = (float)pos_ids[row0 + j] * invf;
                const float c = __cosf(th), sn = __sinf(th);
                const float y = XB[((((wm * 4 + mm) * 4 + ls) * 4 + j) * 16) + lr];
                acc[mm][0][j] = acc[mm][0][j] * c + y * sn;
            }
        }
    }

#pragma unroll
    for (int n = 0; n < 3; n++) {
        const int off = wn * 48 + n * 16;
        int which, d0;
        if (evenbx) { which = (off < 128) ? 0 : 1; d0 = (off < 128) ? off : off - 128; }
        else        { which = (off < 64) ? 1 : 2;  d0 = (off < 64) ? off + 64 : off - 64; }
#pragma unroll
        for (int mm = 0; mm < 4; mm++) {
            const int row0 = (int)m0 + wm * 64 + mm * 16 + ls * 4;
            const int b = row0 >> 11, s0 = row0 & 2047;
            const size_t bh = (size_t)(b * NH_ + nh);
            if (which == 2) {                    // V -> V^T[bh][d][s]
                bf16_t o[4];
#pragma unroll
                for (int j = 0; j < 4; j++) o[j] = f2b(acc[mm][n][j]);
                *(uint2*)&Vt[(bh * HS_ + d0 + lr) * S_ + s0] = *(const uint2*)o;
            } else {
                bf16_t* O = which ? Ko : Qo;
#pragma unroll
                for (int j = 0; j < 4; j++)
                    O[(bh * S_ + s0 + j) * HS_ + d0 + lr] = f2b(acc[mm][n][j]);
            }
        }
    }
}

// ---------------- causal flash attention (r8 structure, best known) ---------
__device__ __forceinline__ void attn_stage(bf16_t* Kd, bf16_t* Vd,
                                           const bf16_t* Kg, const bf16_t* Vg,
                                           int kv0, int wid, int lane) {
#pragma unroll
    for (int jj = 0; jj < 4; jj++) {
        const int c = (wid << 2) + jj;
        const int rk = (c << 2) + (lane >> 4);        // K row 0..63
        async16(Kd + c * 512,
                Kg + (size_t)(kv0 + rk) * HS_ + (((lane & 15) ^ (rk & 7)) << 3));
        const int rv = (c << 3) + (lane >> 3);        // V^T row 0..127
        async16(Vd + c * 512,
                Vg + (size_t)rv * S_ + kv0 + (((lane & 7) ^ (rv & 7)) << 3));
    }
}

__global__ __launch_bounds__(256) void attn_fwd(const bf16_t* __restrict__ Q,
                                                const bf16_t* __restrict__ Kv,
                                                const bf16_t* __restrict__ Vt,
                                                const float* __restrict__ amask,
                                                bf16_t* __restrict__ ctx) {
    __shared__ __align__(16) bf16_t Ks[2][64 * 128];
    __shared__ __align__(16) bf16_t Vs[2][128 * 64];
    __shared__ __align__(16) bf16_t Ps[4][16 * 72];

    const int id = (int)(blockIdx.x + (blockIdx.y << 4));     // 0..511
    const int wg = ((id & 7) << 6) + (id >> 3);               // XCD-bijective
    const int pair = wg & 15;
    const int bh = wg >> 4;
    const int b = bh >> 4, h = bh & 15;
    const int tid = threadIdx.x, wid = tid >> 6, lane = tid & 63;
    const int lr = lane & 15, ls = lane >> 4;
    const float* am = amask + (size_t)b * S_;
    const bf16_t* Kg = Kv + (size_t)bh * S_ * HS_;
    const bf16_t* Vg = Vt + (size_t)bh * HS_ * S_;

#pragma unroll 1
    for (int half = 0; half < 2; ++half) {
        const int qt = half ? pair : (31 - pair);
        const int q0 = qt << 6;
        const int qrow = q0 + wid * 16 + lr;     // this lane's q-row

        bf16x8 qf[4];
        const bf16_t* qp = Q + ((size_t)bh * S_ + qrow) * HS_;
#pragma unroll
        for (int dk = 0; dk < 4; dk++) qf[dk] = *(const bf16x8*)(qp + dk * 32 + ls * 8);

        float mrun = -3.0e38f, lrun = 0.f;
        f32x4 oacc[8];
#pragma unroll
        for (int dt = 0; dt < 8; dt++) oacc[dt] = (f32x4){0.f, 0.f, 0.f, 0.f};

        attn_stage(Ks[0], Vs[0], Kg, Vg, 0, wid, lane);

#pragma unroll 1
        for (int step = 0; step <= qt; ++step) {
            const int cur = step & 1;
            const int kv0 = step << 6;
            if (step < qt) {
                attn_stage(Ks[cur ^ 1], Vs[cur ^ 1], Kg, Vg, (step + 1) << 6, wid, lane);
                WAIT_VM8();
            } else {
                WAIT_VM0();
            }
            BAR();

            // swapped QK^T
            f32x4 sacc[4];
#pragma unroll
            for (int t = 0; t < 4; t++) sacc[t] = (f32x4){0.f, 0.f, 0.f, 0.f};
#pragma unroll
            for (int t = 0; t < 4; t++)
#pragma unroll
                for (int dk = 0; dk < 4; dk++) {
                    const int row = t * 16 + lr;
                    bf16x8 kf = *(const bf16x8*)
                        &Ks[cur][row * 128 + (((dk * 4 + ls) ^ (row & 7)) << 3)];
                    sacc[t] = mfma16(kf, qf[dk], sacc[t]);
                }

            const bool diag = (step == qt);
            float sv[4][4];
            float rmax = -3.0e38f;
#pragma unroll
            for (int t = 0; t < 4; t++) {
                const float4 amv = *(const float4*)&am[kv0 + t * 16 + ls * 4];
                const float amj[4] = { amv.x, amv.y, amv.z, amv.w };
#pragma unroll
                for (int j = 0; j < 4; j++) {
                    const int kvp = kv0 + t * 16 + ls * 4 + j;
                    float v = sacc[t][j] * NORM_ + amj[j];
                    if (diag && kvp > qrow) v = -3.0e38f;
                    sv[t][j] = v;
                    rmax = fmaxf(rmax, v);
                }
            }
            rmax = fmaxf(rmax, __shfl_xor(rmax, 16));
            rmax = fmaxf(rmax, __shfl_xor(rmax, 32));

            if (!__all((int)(rmax <= mrun))) {
                const float mnew = fmaxf(mrun, rmax);
                const float sc = __expf(mrun - mnew);
                lrun *= sc;
                mrun = mnew;
                float scb[4];
#pragma unroll
                for (int j = 0; j < 4; j++) scb[j] = __shfl(sc, ls * 4 + j);
#pragma unroll
                for (int dt = 0; dt < 8; dt++)
#pragma unroll
                    for (int j = 0; j < 4; j++) oacc[dt][j] *= scb[j];
            }

            float psum = 0.f;
#pragma unroll
            for (int t = 0; t < 4; t++) {
                const float p0 = __expf(sv[t][0] - mrun);
                const float p1 = __expf(sv[t][1] - mrun);
                const float p2 = __expf(sv[t][2] - mrun);
                const float p3 = __expf(sv[t][3] - mrun);
                psum += (p0 + p1) + (p2 + p3);
                const unsigned pk0 = (unsigned)f2b(p0) | ((unsigned)f2b(p1) << 16);
                const unsigned pk1 = (unsigned)f2b(p2) | ((unsigned)f2b(p3) << 16);
                *(unsigned*)&Ps[wid][lr * 72 + t * 16 + ls * 4]     = pk0;
                *(unsigned*)&Ps[wid][lr * 72 + t * 16 + ls * 4 + 2] = pk1;
            }
            psum += __shfl_xor(psum, 16);
            psum += __shfl_xor(psum, 32);
            lrun += psum;

            bf16x8 pf[2];
#pragma unroll
            for (int hh = 0; hh < 2; hh++)
                pf[hh] = *(const bf16x8*)&Ps[wid][lr * 72 + hh * 32 + ls * 8];
#pragma unroll
            for (int dt = 0; dt < 8; dt++)
#pragma unroll
                for (int hh = 0; hh < 2; hh++) {
                    const int vrow = dt * 16 + lr;
                    bf16x8 vf = *(const bf16x8*)
                        &Vs[cur][vrow * 64 + (((hh * 4 + ls) ^ (vrow & 7)) << 3)];
                    oacc[dt] = mfma16(pf[hh], vf, oacc[dt]);
                }
            BAR();
        }

        const float inv = 1.0f / lrun;           // q=lr layout
        float invj[4];
#pragma unroll
        for (int j = 0; j < 4; j++) invj[j] = __shfl(inv, ls * 4 + j);
#pragma unroll
        for (int j = 0; j < 4; j++) {
            bf16_t* dst = ctx + ((size_t)b * S_ + q0 + wid * 16 + ls * 4 + j) * H_ + h * HS_;
#pragma unroll
            for (int dt = 0; dt < 8; dt++) dst[dt * 16 + lr] = f2b(oacc[dt][j] * invj[j]);
        }
    }
}

extern "C" void kernel_launch(void* const* d_in, const int* in_sizes, int n_in,
                              void* d_out, int out_size, void* d_ws, size_t ws_size,
                              hipStream_t stream) {
    const float* hs   = (const float*)d_in[0];
    const float* am   = (const float*)d_in[1];
    const int*   pos  = (const int*)d_in[2];
    const float* Wqkv = (const float*)d_in[3];
    const float* bqkv = (const float*)d_in[4];
    const float* Wd   = (const float*)d_in[5];
    const float* bd   = (const float*)d_in[6];
    float* out = (float*)d_out;
    char*  ws  = (char*)d_ws;

    const size_t MB = 1024 * 1024;
    bf16_t* X    = (bf16_t*)(ws);              // 16 MB (reused as ctx)
    bf16_t* WqT  = (bf16_t*)(ws + 16 * MB);    // 24 MB
    bf16_t* WdT  = (bf16_t*)(ws + 40 * MB);    // 8 MB
    bf16_t* Qb   = (bf16_t*)(ws + 48 * MB);    // 16 MB
    bf16_t* Kb   = (bf16_t*)(ws + 64 * MB);    // 16 MB
    bf16_t* Vtb  = (bf16_t*)(ws + 80 * MB);    // 16 MB
    bf16_t* ctx  = X;

    prep<<<8192, 256, 0, stream>>>(hs, X, Wqkv, WqT, Wd, WdT);
    gemm_qkv_fused<<<dim3(32, 32), 512, 0, stream>>>(X, WqT, bqkv, pos,
                                                     Qb, Kb, Vtb, 4096, 6144, 2048);
    attn_fwd<<<dim3(16, 32), 256, 0, stream>>>(Qb, Kb, Vtb, am, ctx);
    gemm_dense<<<dim3(16, 32), 512, 0, stream>>>(ctx, WdT, bd, out, 4096, 2048, 2048);
}